// Round 11
// baseline (450.215 us; speedup 1.0000x reference)
//
#include <hip/hip_runtime.h>
#include <hip/hip_bf16.h>

// GCN 2-layer encoder, N=100000 nodes, C=128 features, E=1.6M edges.
// out[N,256] = concat(relu(gcn(x,W1,b1)), relu(gcn(relu1,W2,b2)))
// gcn: h=XW; agg[d] = sum_{(s,d) in A+I} h[s]*dinv[s]*dinv[d]; +b
// dinv = rsqrt(1 + in_degree(dst))
//
// R1 -> R2: multi-block scan (was 190us single-block, 0.17% occupancy).
// R2 -> R3: h stored packed bf16 (gather 512B->256B rows) + edge loop x4.
// R3 -> R4: GEMM on MFMA via split-bf16 3-term product (fp32-like accuracy).
// R4 -> R6: CSR build: pos-pass + atomic-free scatter; agg edge batch x8.
// R7 -> R8: GEMM LDS staging deleted (direct A-frag global loads, split2 at
//           consumer; no barrier, no LDS). Aggregate: 2 edges/wave via uint2
//           gathers + shfl_xor(32) combine (edge-loop overhead halved; was
//           71us @ 41% VALU, 3.55TB/s). pos_kernel int4 x4 atomic chains.

#define FEAT 128
#define HW 64   // packed words per h row

typedef __attribute__((ext_vector_type(8))) short short8;   // 8 bf16
typedef __attribute__((ext_vector_type(4))) float f32x4;

static __device__ inline unsigned pack_bf16(float a, float b) {
    unsigned ua = __float_as_uint(a), ub = __float_as_uint(b);
    ua = (ua + 0x7fff + ((ua >> 16) & 1)) >> 16;   // RNE
    ub = (ub + 0x7fff + ((ub >> 16) & 1)) >> 16;
    return (ua & 0xffffu) | (ub << 16);
}

// split x = hi + lo, both bf16 (RNE); residual ~2^-18 relative
static __device__ inline void split2(float x, unsigned short* hi, unsigned short* lo) {
    unsigned u = __float_as_uint(x);
    unsigned uh = (u + 0x7fff + ((u >> 16) & 1)) & 0xffff0000u;
    *hi = (unsigned short)(uh >> 16);
    float lo_f = x - __uint_as_float(uh);
    unsigned ul = __float_as_uint(lo_f);
    *lo = (unsigned short)((ul + 0x7fff + ((ul >> 16) & 1)) >> 16);
}

static __device__ inline float bl(unsigned v) { return __uint_as_float(v << 16); }
static __device__ inline float bh(unsigned v) { return __uint_as_float(v & 0xffff0000u); }

// ---------------- CSR build ----------------

// Pass 1: per-edge slot via atomic; 4 independent atomic chains per thread.
__global__ void pos_kernel(const int* __restrict__ dst, int E,
                           int* __restrict__ cnt, int* __restrict__ pos) {
    int t = blockIdx.x * 256 + threadIdx.x;
    int stride = gridDim.x * 256;
    int E4 = E >> 2;
    const int4* d4 = (const int4*)dst;
    int4* p4 = (int4*)pos;
    for (int i = t; i < E4; i += stride) {
        int4 d = d4[i];
        int4 p;
        p.x = atomicAdd(&cnt[d.x], 1);
        p.y = atomicAdd(&cnt[d.y], 1);
        p.z = atomicAdd(&cnt[d.z], 1);
        p.w = atomicAdd(&cnt[d.w], 1);
        p4[i] = p;
    }
    for (int e = E4 * 4 + t; e < E; e += stride) {
        pos[e] = atomicAdd(&cnt[dst[e]], 1);
    }
}

__global__ __launch_bounds__(1024) void scan_block_kernel(
    const int* __restrict__ cnt, int* __restrict__ incl,
    int* __restrict__ bsum, float* __restrict__ dinv, int N) {
    __shared__ int s[1024];
    int tid = threadIdx.x;
    int i = blockIdx.x * 1024 + tid;
    int v = (i < N) ? cnt[i] : 0;
    if (i < N) dinv[i] = rsqrtf((float)(v + 1));  // +1 self loop
    s[tid] = v;
    __syncthreads();
    for (int off = 1; off < 1024; off <<= 1) {
        int add = (tid >= off) ? s[tid - off] : 0;
        __syncthreads();
        s[tid] += add;
        __syncthreads();
    }
    if (i < N) incl[i] = s[tid];
    if (tid == 1023) bsum[blockIdx.x] = s[1023];
}

__global__ __launch_bounds__(128) void scan_bsum_kernel(int* __restrict__ bsum, int NB) {
    __shared__ int s[128];
    int tid = threadIdx.x;
    int v = (tid < NB) ? bsum[tid] : 0;
    s[tid] = v;
    __syncthreads();
    for (int off = 1; off < 128; off <<= 1) {
        int add = (tid >= off) ? s[tid - off] : 0;
        __syncthreads();
        s[tid] += add;
        __syncthreads();
    }
    if (tid < NB) bsum[tid] = s[tid] - v;  // exclusive
}

__global__ void scan_finalize_kernel(const int* __restrict__ incl,
                                     const int* __restrict__ bsum,
                                     int* __restrict__ rowptr, int N) {
    int i = blockIdx.x * 256 + threadIdx.x;
    if (i < N) rowptr[i + 1] = incl[i] + bsum[i >> 10];
    if (i == 0) rowptr[0] = 0;
}

// Pass 2: atomic-free scatter, 4 independent store chains per thread.
__global__ void scatter_kernel(const int* __restrict__ src, const int* __restrict__ dst,
                               const int* __restrict__ pos, const int* __restrict__ rowptr,
                               int* __restrict__ csr_src, int E) {
    int t = blockIdx.x * 256 + threadIdx.x;
    int stride = gridDim.x * 256;
    int E4 = E >> 2;
    const int4* s4 = (const int4*)src;
    const int4* d4 = (const int4*)dst;
    const int4* p4 = (const int4*)pos;
    for (int i = t; i < E4; i += stride) {
        int4 d = d4[i], s = s4[i], p = p4[i];
        csr_src[rowptr[d.x] + p.x] = s.x;
        csr_src[rowptr[d.y] + p.y] = s.y;
        csr_src[rowptr[d.z] + p.z] = s.z;
        csr_src[rowptr[d.w] + p.w] = s.w;
    }
    for (int e = E4 * 4 + t; e < E; e += stride) {
        csr_src[rowptr[dst[e]] + pos[e]] = src[e];
    }
}

// ---------------- W pre-swizzle into B-fragment order (both layers) ----------------
// frag elem f = ((ks*8 + t)*64 + lane)*8 + j  ->  W[ks*32+(lane>>4)*8+j][t*16+(lane&15)]

__global__ void prep_w_kernel(const float* __restrict__ W1, const float* __restrict__ W2,
                              unsigned short* __restrict__ wf1_hi, unsigned short* __restrict__ wf1_lo,
                              unsigned short* __restrict__ wf2_hi, unsigned short* __restrict__ wf2_lo) {
    int g = blockIdx.x * 256 + threadIdx.x;   // 0..32767
    int f = g & 16383;
    int j = f & 7, lane = (f >> 3) & 63, t = (f >> 9) & 7, ks = f >> 12;
    int k = ks * 32 + (lane >> 4) * 8 + j;
    int n = t * 16 + (lane & 15);
    unsigned short hi, lo;
    if (g < 16384) {
        split2(W1[k * 128 + n], &hi, &lo);
        wf1_hi[f] = hi; wf1_lo[f] = lo;
    } else {
        split2(W2[k * 128 + n], &hi, &lo);
        wf2_hi[f] = hi; wf2_lo[f] = lo;
    }
}

// ---------------- MFMA GEMM: H = pack_bf16_perm( X[M,ldx(0:128)] @ W ) ----------------
// 64 rows/block, 4 waves, each wave 16 rows x 128 cols. NO LDS: A-frag rows
// loaded directly from global (one full 128B line per (row,ks) per wave),
// split2 at consumer. 3-term split-bf16: acc += Ahi*Bhi + Ahi*Blo + Alo*Bhi.

__global__ __launch_bounds__(256) void gemm_mfma_kernel(const float* __restrict__ X, int ldx,
    const unsigned short* __restrict__ wf_hi, const unsigned short* __restrict__ wf_lo,
    unsigned* __restrict__ H, int M) {
    int tid = threadIdx.x;
    int wave = tid >> 6, lane = tid & 63;
    int row0 = blockIdx.x * 64;
    int arow = row0 + wave * 16 + (lane & 15);
    int crow = (arow < M) ? arow : (M - 1);   // clamp load addr; garbage rows
    const float* xrow = X + (size_t)crow * ldx;   // never reach the D-store
    int kgrp = (lane >> 4) * 8;

    f32x4 acc[8];
#pragma unroll
    for (int t = 0; t < 8; ++t) acc[t] = (f32x4){0.f, 0.f, 0.f, 0.f};

#pragma unroll
    for (int ks = 0; ks < 4; ++ks) {
        int k0 = ks * 32 + kgrp;
        float4 xa = *(const float4*)(xrow + k0);
        float4 xb = *(const float4*)(xrow + k0 + 4);
        unsigned short h8[8], l8[8];
        split2(xa.x, &h8[0], &l8[0]); split2(xa.y, &h8[1], &l8[1]);
        split2(xa.z, &h8[2], &l8[2]); split2(xa.w, &h8[3], &l8[3]);
        split2(xb.x, &h8[4], &l8[4]); split2(xb.y, &h8[5], &l8[5]);
        split2(xb.z, &h8[6], &l8[6]); split2(xb.w, &h8[7], &l8[7]);
        short8 a_hi, a_lo;
#pragma unroll
        for (int j = 0; j < 8; ++j) { a_hi[j] = (short)h8[j]; a_lo[j] = (short)l8[j]; }
        const unsigned short* bp = wf_hi + ((size_t)(ks * 8) * 64 + lane) * 8;
        const unsigned short* bq = wf_lo + ((size_t)(ks * 8) * 64 + lane) * 8;
#pragma unroll
        for (int t = 0; t < 8; ++t) {
            short8 b_hi = *(const short8*)(bp + t * 512);
            short8 b_lo = *(const short8*)(bq + t * 512);
            acc[t] = __builtin_amdgcn_mfma_f32_16x16x32_bf16(a_hi, b_hi, acc[t], 0, 0, 0);
            acc[t] = __builtin_amdgcn_mfma_f32_16x16x32_bf16(a_hi, b_lo, acc[t], 0, 0, 0);
            acc[t] = __builtin_amdgcn_mfma_f32_16x16x32_bf16(a_lo, b_hi, acc[t], 0, 0, 0);
        }
    }

    // D layout: row=(lane>>4)*4+r, col=lane&15 (per tile t -> feat t*16+col).
    // Pack feats (2j*16+c, (2j+1)*16+c) into word j*16+c.
    int rbase = row0 + wave * 16 + (lane >> 4) * 4;
    int c = lane & 15;
#pragma unroll
    for (int r = 0; r < 4; ++r) {
        int gr = rbase + r;
        if (gr < M) {
#pragma unroll
            for (int j = 0; j < 4; ++j) {
                H[(size_t)gr * HW + j * 16 + c] = pack_bf16(acc[2 * j][r], acc[2 * j + 1][r]);
            }
        }
    }
}

// ---------------- aggregation: one wave per dst node, 2 edges/wave ----------------
// Lane halves process alternating edges; each lane gathers uint2 (words 2li,
// 2li+1 of the 64-word row). Cross-half combine via shfl_xor(32).
// H word w holds feats f0=32*(w>>4)+(w&15) (low), f0+16 (high).

__global__ __launch_bounds__(256) void aggregate_kernel(const unsigned* __restrict__ H,
    const float* __restrict__ dinv, const int* __restrict__ rowptr,
    const int* __restrict__ csr_src, const float* __restrict__ bias,
    float* __restrict__ out, int ldo, int coloff, int N) {
    int node = blockIdx.x * 4 + (threadIdx.x >> 6);
    if (node >= N) return;
    int lane = threadIdx.x & 63;
    int half = lane >> 5;
    int li = lane & 31;
    int w0 = 2 * li, w1 = 2 * li + 1;

    float di = dinv[node];
    float a0x = 0.f, a0y = 0.f, a1x = 0.f, a1y = 0.f;
    if (half == 0) {   // self-loop term, counted once
        uint2 v = *(const uint2*)(H + (size_t)node * HW + w0);
        a0x = bl(v.x) * di; a0y = bh(v.x) * di;
        a1x = bl(v.y) * di; a1y = bh(v.y) * di;
    }

    int e0 = rowptr[node], e1 = rowptr[node + 1];
    int e = e0 + half;
    // 8 edges per joint iteration (4 per half)
    for (; e + 6 < e1; e += 8) {
        int s[4]; float ws[4]; uint2 v[4];
#pragma unroll
        for (int i = 0; i < 4; ++i) s[i] = csr_src[e + 2 * i];
#pragma unroll
        for (int i = 0; i < 4; ++i) ws[i] = dinv[s[i]];
#pragma unroll
        for (int i = 0; i < 4; ++i) v[i] = *(const uint2*)(H + (size_t)s[i] * HW + w0);
#pragma unroll
        for (int i = 0; i < 4; ++i) {
            a0x = fmaf(bl(v[i].x), ws[i], a0x);
            a0y = fmaf(bh(v[i].x), ws[i], a0y);
            a1x = fmaf(bl(v[i].y), ws[i], a1x);
            a1y = fmaf(bh(v[i].y), ws[i], a1y);
        }
    }
    for (; e < e1; e += 2) {
        int s = csr_src[e];
        float ws = dinv[s];
        uint2 v = *(const uint2*)(H + (size_t)s * HW + w0);
        a0x = fmaf(bl(v.x), ws, a0x);
        a0y = fmaf(bh(v.x), ws, a0y);
        a1x = fmaf(bl(v.y), ws, a1x);
        a1y = fmaf(bh(v.y), ws, a1y);
    }

    // combine halves
    a0x += __shfl_xor(a0x, 32);
    a0y += __shfl_xor(a0y, 32);
    a1x += __shfl_xor(a1x, 32);
    a1y += __shfl_xor(a1y, 32);

    if (half == 0) {
        float* orow = out + (size_t)node * ldo + coloff;
        int f0 = 32 * (w0 >> 4) + (w0 & 15);
        int g0 = 32 * (w1 >> 4) + (w1 & 15);
        orow[f0]      = fmaxf(a0x * di + bias[f0], 0.f);
        orow[f0 + 16] = fmaxf(a0y * di + bias[f0 + 16], 0.f);
        orow[g0]      = fmaxf(a1x * di + bias[g0], 0.f);
        orow[g0 + 16] = fmaxf(a1y * di + bias[g0 + 16], 0.f);
    }
}

// ---------------- launch ----------------

extern "C" void kernel_launch(void* const* d_in, const int* in_sizes, int n_in,
                              void* d_out, int out_size, void* d_ws, size_t ws_size,
                              hipStream_t stream) {
    const float* x  = (const float*)d_in[0];
    const int*   ei = (const int*)d_in[1];   // int32 on device (JAX x64 disabled)
    const float* W1 = (const float*)d_in[2];
    const float* b1 = (const float*)d_in[3];
    const float* W2 = (const float*)d_in[4];
    const float* b2 = (const float*)d_in[5];
    float* out = (float*)d_out;

    const int N = in_sizes[0] / FEAT;   // 100000
    const int E = in_sizes[1] / 2;      // 1600000
    const int* srcs = ei;
    const int* dsts = ei + E;

    const int NB = (N + 1023) / 1024;   // scan blocks (98 <= 128)

    // workspace layout (16B-aligned chunks)
    char* w = (char*)d_ws;
    unsigned* hb  = (unsigned*)w; w += (size_t)N * HW * sizeof(unsigned);  // 25.6 MB
    float* dinv   = (float*)w; w += (size_t)N * sizeof(float);
    int*   cnt    = (int*)w;   w += (size_t)N * sizeof(int);
    int*   rowptr = (int*)w;   w += (size_t)(N + 4) * sizeof(int);
    int*   csr    = (int*)w;   w += (size_t)E * sizeof(int);
    int*   pos    = (int*)w;   w += (size_t)E * sizeof(int);
    int*   incl   = (int*)w;   w += (size_t)N * sizeof(int);
    int*   bsum   = (int*)w;   w += 128 * sizeof(int);
    unsigned short* wf1_hi = (unsigned short*)w; w += 16384 * sizeof(unsigned short);
    unsigned short* wf1_lo = (unsigned short*)w; w += 16384 * sizeof(unsigned short);
    unsigned short* wf2_hi = (unsigned short*)w; w += 16384 * sizeof(unsigned short);
    unsigned short* wf2_lo = (unsigned short*)w; w += 16384 * sizeof(unsigned short);

    hipMemsetAsync(cnt, 0, (size_t)N * sizeof(int), stream);

    int ng = (N + 255) / 256;
    prep_w_kernel<<<128, 256, 0, stream>>>(W1, W2, wf1_hi, wf1_lo, wf2_hi, wf2_lo);
    pos_kernel<<<1024, 256, 0, stream>>>(dsts, E, cnt, pos);
    scan_block_kernel<<<NB, 1024, 0, stream>>>(cnt, incl, bsum, dinv, N);
    scan_bsum_kernel<<<1, 128, 0, stream>>>(bsum, NB);
    scan_finalize_kernel<<<ng, 256, 0, stream>>>(incl, bsum, rowptr, N);
    scatter_kernel<<<1024, 256, 0, stream>>>(srcs, dsts, pos, rowptr, csr, E);

    int gg = (N + 63) / 64;
    int ag = (N + 3) / 4;
    // layer 1
    gemm_mfma_kernel<<<gg, 256, 0, stream>>>(x, FEAT, wf1_hi, wf1_lo, hb, N);
    aggregate_kernel<<<ag, 256, 0, stream>>>(hb, dinv, rowptr, csr, b1, out, 2 * FEAT, 0, N);
    // layer 2 (input = out cols 0..127, row stride 256)
    gemm_mfma_kernel<<<gg, 256, 0, stream>>>(out, 2 * FEAT, wf2_hi, wf2_lo, hb, N);
    aggregate_kernel<<<ag, 256, 0, stream>>>(hb, dinv, rowptr, csr, b2, out, 2 * FEAT, FEAT, N);
}